// Round 5
// baseline (156.357 us; speedup 1.0000x reference)
//
#include <hip/hip_runtime.h>

#define A_N 256
#define F_N 256
#define C_N 32

typedef __attribute__((ext_vector_type(8))) short bf16x8;
typedef __attribute__((ext_vector_type(4))) float f32x4;
typedef __attribute__((ext_vector_type(8))) unsigned short ushort8;

__device__ __forceinline__ unsigned short f2bf(float x) {
  union { float f; unsigned u; } v; v.f = x;
  unsigned r = v.u + 0x7FFF + ((v.u >> 16) & 1);  // round-to-nearest-even
  return (unsigned short)(r >> 16);
}

// ---------------------------------------------------------------------------
// Kernel 1: LayerNorm + dual projections (+mask). One block per node.
// Writes left as bf16 [a][c] (A-fragment source) and right as f32 [a][c].
// ---------------------------------------------------------------------------
__global__ __launch_bounds__(256) void ln_proj_kernel(
    const float* __restrict__ node_vec, const float* __restrict__ node_mask,
    const float* __restrict__ ln_scale, const float* __restrict__ ln_bias,
    const float* __restrict__ Wl, const float* __restrict__ bl,
    const float* __restrict__ Wr, const float* __restrict__ br,
    unsigned short* __restrict__ leftbf, float* __restrict__ right) {
  const int a = blockIdx.x;
  const int t = threadIdx.x;
  __shared__ float sAct[F_N];
  __shared__ float sRed[8];
  __shared__ float sPl[8][C_N];
  __shared__ float sPr[8][C_N];

  float x = node_vec[a * F_N + t];

  float s = x;
  for (int off = 32; off; off >>= 1) s += __shfl_down(s, off, 64);
  const int wave = t >> 6, lane = t & 63;
  if (lane == 0) sRed[wave] = s;
  __syncthreads();
  if (t == 0) sRed[4] = (sRed[0] + sRed[1] + sRed[2] + sRed[3]) * (1.0f / F_N);
  __syncthreads();
  const float mu = sRed[4];
  const float d = x - mu;

  s = d * d;
  for (int off = 32; off; off >>= 1) s += __shfl_down(s, off, 64);
  if (lane == 0) sRed[wave] = s;
  __syncthreads();
  if (t == 0) {
    float v = (sRed[0] + sRed[1] + sRed[2] + sRed[3]) * (1.0f / F_N);
    sRed[5] = rsqrtf(v + 1e-5f);
  }
  __syncthreads();
  const float act = d * sRed[5] * ln_scale[t] + ln_bias[t];
  sAct[t] = act;
  __syncthreads();

  const int c = t & 31, seg = t >> 5;
  float pl = 0.f, pr = 0.f;
  const float* actp = &sAct[seg * 32];
#pragma unroll
  for (int j = 0; j < 32; ++j) {
    const float av = actp[j];
    const int widx = (seg * 32 + j) * C_N + c;
    pl = fmaf(av, Wl[widx], pl);
    pr = fmaf(av, Wr[widx], pr);
  }
  sPl[seg][c] = pl;
  sPr[seg][c] = pr;
  __syncthreads();
  if (t < C_N) {
    const float m = node_mask[a];
    float suml = bl[t], sumr = br[t];
#pragma unroll
    for (int sg = 0; sg < 8; ++sg) { suml += sPl[sg][t]; sumr += sPr[sg][t]; }
    leftbf[a * C_N + t] = f2bf(suml * m);
    right[a * C_N + t] = sumr * m;
  }
}

// ---------------------------------------------------------------------------
// Kernel 2: T[c][b][f] = sum_d right[b][d]*Wo[c*32+d][f], written as bf16 in
// MFMA B-fragment order:  elem(c, b, f) lives at
//   ushort8[(b*16 + f/16)*64 + (c/8)*16 + (f&15)][c&7]
// so k3's B-frag load is ONE coalesced global_load_dwordx4 per wave.
// No LDS. right[] read via uniform (scalar) loads. One block per b.
// Thread t: fq = t&63 -> f = 4*fq+q (q=0..3), cq = t>>6 -> c = 8*cq+ci.
// ---------------------------------------------------------------------------
__global__ __launch_bounds__(256) void compT_kernel(
    const float* __restrict__ right, const float* __restrict__ Wo,
    unsigned short* __restrict__ T2) {
  const int b = blockIdx.x;
  const int t = threadIdx.x;
  const int fq = t & 63;
  const int cq = t >> 6;

  float rv[C_N];
#pragma unroll
  for (int d = 0; d < C_N; ++d) rv[d] = right[b * C_N + d];

  const f32x4* Wo4 = (const f32x4*)Wo;
  f32x4 acc[8];
#pragma unroll
  for (int ci = 0; ci < 8; ++ci) acc[ci] = (f32x4){0.f, 0.f, 0.f, 0.f};

#pragma unroll
  for (int d = 0; d < C_N; ++d) {
#pragma unroll
    for (int ci = 0; ci < 8; ++ci) {
      const f32x4 w = Wo4[(size_t)((8 * cq + ci) * C_N + d) * 64 + fq];
      acc[ci] += rv[d] * w;
    }
  }

  const int ft = fq >> 2;
  ushort8* T8 = (ushort8*)T2;
#pragma unroll
  for (int q = 0; q < 4; ++q) {
    const int l = cq * 16 + 4 * (fq & 3) + q;
    ushort8 o;
#pragma unroll
    for (int ci = 0; ci < 8; ++ci) o[ci] = f2bf(acc[ci][q]);
    T8[(size_t)(b * 16 + ft) * 64 + l] = o;
  }
}

// ---------------------------------------------------------------------------
// Kernel 3: out[a][b*256+f] = bo[f] + (L @ T2)  via mfma_f32_16x16x32_bf16.
// Grid (2 a-halves, 256 b) x 256 threads. No LDS. Wave w owns ftiles 4w..4w+3
// and 8 atiles. A-frag: lane holds L[a0+(l&15)][(l>>4)*8+j]; B-frag: lane holds
// T[(l>>4)*8+j][f0+(l&15)] (pre-arranged by k2); D: col=l&15, row=(l>>4)*4+i.
// ---------------------------------------------------------------------------
__global__ __launch_bounds__(256) void out_mfma_kernel(
    const unsigned short* __restrict__ leftbf,
    const unsigned short* __restrict__ T2,
    const float* __restrict__ bo, float* __restrict__ out) {
  const int ah = blockIdx.x;   // a-half (128 rows)
  const int b = blockIdx.y;
  const int t = threadIdx.x;
  const int w = t >> 6;
  const int l = t & 63;
  const int lr = l & 15;   // A row / B,D col within tile
  const int lk = l >> 4;   // k-octet / D row-quad

  bf16x8 afrag[8];
#pragma unroll
  for (int m = 0; m < 8; ++m) {
    const int a = ah * 128 + m * 16 + lr;
    afrag[m] = *(const bf16x8*)(leftbf + a * C_N + lk * 8);
  }

  bf16x8 bfrag[4];
  float bv[4];
#pragma unroll
  for (int q = 0; q < 4; ++q) {
    const int ft = w * 4 + q;
    bfrag[q] = *(const bf16x8*)(T2 + ((size_t)(b * 16 + ft) * 64 + l) * 8);
    bv[q] = bo[ft * 16 + lr];
  }

  const size_t rowstride = (size_t)A_N * F_N;  // 65536
#pragma unroll
  for (int q = 0; q < 4; ++q) {
    const int ft = w * 4 + q;
    const int col = b * F_N + ft * 16 + lr;
    f32x4 acc[8];
#pragma unroll
    for (int m = 0; m < 8; ++m)
      acc[m] = (f32x4){bv[q], bv[q], bv[q], bv[q]};
#pragma unroll
    for (int m = 0; m < 8; ++m)
      acc[m] = __builtin_amdgcn_mfma_f32_16x16x32_bf16(afrag[m], bfrag[q], acc[m], 0, 0, 0);
#pragma unroll
    for (int m = 0; m < 8; ++m) {
      const int arow = ah * 128 + m * 16 + lk * 4;
#pragma unroll
      for (int i = 0; i < 4; ++i)
        out[(size_t)(arow + i) * rowstride + col] = acc[m][i];
    }
  }
}

extern "C" void kernel_launch(void* const* d_in, const int* in_sizes, int n_in,
                              void* d_out, int out_size, void* d_ws, size_t ws_size,
                              hipStream_t stream) {
  const float* node_vec  = (const float*)d_in[0];
  const float* node_mask = (const float*)d_in[1];
  const float* ln_scale  = (const float*)d_in[2];
  const float* ln_bias   = (const float*)d_in[3];
  const float* Wl        = (const float*)d_in[4];
  const float* bl        = (const float*)d_in[5];
  const float* Wr        = (const float*)d_in[6];
  const float* br        = (const float*)d_in[7];
  const float* Wo        = (const float*)d_in[8];
  const float* bo        = (const float*)d_in[9];
  float* out = (float*)d_out;

  // ws layout: right f32 (32KB) | leftbf bf16 (16KB) | pad | T2 bf16 frag (4MB)
  float* right           = (float*)d_ws;
  unsigned short* leftbf = (unsigned short*)(right + A_N * C_N);
  unsigned short* T2     = (unsigned short*)((char*)d_ws + 65536);

  ln_proj_kernel<<<A_N, 256, 0, stream>>>(node_vec, node_mask, ln_scale, ln_bias,
                                          Wl, bl, Wr, br, leftbf, right);
  compT_kernel<<<A_N, 256, 0, stream>>>(right, Wo, T2);
  out_mfma_kernel<<<dim3(2, A_N), 256, 0, stream>>>(leftbf, T2, bo, out);
}

// Round 6
// 112.735 us; speedup vs baseline: 1.3869x; 1.3869x over previous
//
#include <hip/hip_runtime.h>

#define A_N 256
#define F_N 256
#define C_N 32

typedef __attribute__((ext_vector_type(8))) short bf16x8;
typedef __attribute__((ext_vector_type(4))) float f32x4;
typedef __attribute__((ext_vector_type(8))) unsigned short ushort8;

__device__ __forceinline__ unsigned short f2bf(float x) {
  union { float f; unsigned u; } v; v.f = x;
  unsigned r = v.u + 0x7FFF + ((v.u >> 16) & 1);  // round-to-nearest-even
  return (unsigned short)(r >> 16);
}

// ---------------------------------------------------------------------------
// Kernel 1: LayerNorm + dual projections (+mask). One block per node.
// left -> bf16 [a][c], right -> f32 [a][c].
// ---------------------------------------------------------------------------
__global__ __launch_bounds__(256) void ln_proj_kernel(
    const float* __restrict__ node_vec, const float* __restrict__ node_mask,
    const float* __restrict__ ln_scale, const float* __restrict__ ln_bias,
    const float* __restrict__ Wl, const float* __restrict__ bl,
    const float* __restrict__ Wr, const float* __restrict__ br,
    unsigned short* __restrict__ leftbf, float* __restrict__ right) {
  const int a = blockIdx.x;
  const int t = threadIdx.x;
  __shared__ float sAct[F_N];
  __shared__ float sRed[8];
  __shared__ float sPl[8][C_N];
  __shared__ float sPr[8][C_N];

  float x = node_vec[a * F_N + t];

  float s = x;
  for (int off = 32; off; off >>= 1) s += __shfl_down(s, off, 64);
  const int wave = t >> 6, lane = t & 63;
  if (lane == 0) sRed[wave] = s;
  __syncthreads();
  if (t == 0) sRed[4] = (sRed[0] + sRed[1] + sRed[2] + sRed[3]) * (1.0f / F_N);
  __syncthreads();
  const float mu = sRed[4];
  const float d = x - mu;

  s = d * d;
  for (int off = 32; off; off >>= 1) s += __shfl_down(s, off, 64);
  if (lane == 0) sRed[wave] = s;
  __syncthreads();
  if (t == 0) {
    float v = (sRed[0] + sRed[1] + sRed[2] + sRed[3]) * (1.0f / F_N);
    sRed[5] = rsqrtf(v + 1e-5f);
  }
  __syncthreads();
  const float act = d * sRed[5] * ln_scale[t] + ln_bias[t];
  sAct[t] = act;
  __syncthreads();

  const int c = t & 31, seg = t >> 5;
  float pl = 0.f, pr = 0.f;
  const float* actp = &sAct[seg * 32];
#pragma unroll
  for (int j = 0; j < 32; ++j) {
    const float av = actp[j];
    const int widx = (seg * 32 + j) * C_N + c;
    pl = fmaf(av, Wl[widx], pl);
    pr = fmaf(av, Wr[widx], pr);
  }
  sPl[seg][c] = pl;
  sPr[seg][c] = pr;
  __syncthreads();
  if (t < C_N) {
    const float m = node_mask[a];
    float suml = bl[t], sumr = br[t];
#pragma unroll
    for (int sg = 0; sg < 8; ++sg) { suml += sPl[sg][t]; sumr += sPr[sg][t]; }
    leftbf[a * C_N + t] = f2bf(suml * m);
    right[a * C_N + t] = sumr * m;
  }
}

// ---------------------------------------------------------------------------
// Kernel 2: T[b][f][c] = sum_d right[b][d] * Wo[c*32+d][f]   (bf16, 4 MB)
// grid (64 btiles x 4 fgroups), 256 thr. Thread: f = fg*64 + (t>>6)*16 + (t&15),
// ci = (t>>4)&3 -> c-octet ci*8..+7, b-tile of 4. Per d: 8 coalesced Wo loads
// + 4x8 FMA; acc = 32 VGPR so the full d-unroll pipelines loads deeply.
// Wo aggregate read = 64 MB (was 256 MB); waves 1024.
// ---------------------------------------------------------------------------
__global__ __launch_bounds__(256) void compT_kernel(
    const float* __restrict__ right, const float* __restrict__ Wo,
    unsigned short* __restrict__ T2) {
  const int b0 = blockIdx.x * 4;
  const int t = threadIdx.x;
  const int f = blockIdx.y * 64 + ((t >> 6) << 4) + (t & 15);
  const int ci = (t >> 4) & 3;

  float acc[4][8];
#pragma unroll
  for (int b = 0; b < 4; ++b)
#pragma unroll
    for (int cj = 0; cj < 8; ++cj) acc[b][cj] = 0.f;

#pragma unroll
  for (int d = 0; d < C_N; ++d) {
    float wv[8];
#pragma unroll
    for (int cj = 0; cj < 8; ++cj)
      wv[cj] = Wo[(size_t)((ci * 8 + cj) * C_N + d) * F_N + f];
#pragma unroll
    for (int b = 0; b < 4; ++b) {
      const float rv = right[(b0 + b) * C_N + d];
#pragma unroll
      for (int cj = 0; cj < 8; ++cj)
        acc[b][cj] = fmaf(rv, wv[cj], acc[b][cj]);
    }
  }

#pragma unroll
  for (int b = 0; b < 4; ++b) {
    ushort8 o;
#pragma unroll
    for (int cj = 0; cj < 8; ++cj) o[cj] = f2bf(acc[b][cj]);
    *(ushort8*)(T2 + ((size_t)(b0 + b) * F_N + f) * C_N + ci * 8) = o;
  }
}

// ---------------------------------------------------------------------------
// Kernel 3: out[a][b*256+f] = bo[f] + sum_c T[b][f][c] * left[a][c]
// via mfma(Tfrag, Lfrag, acc): A-operand = T (M=f), B-operand = left (N=a).
// D: lane holds 4 CONSECUTIVE f for one a -> single float4 store per tile.
// Grid (2 a-halves, 256 b) x 256 thr, no LDS. Per wave: 12 loads, 32 MFMA,
// 32 float4 stores.
// ---------------------------------------------------------------------------
__global__ __launch_bounds__(256) void out_mfma_kernel(
    const unsigned short* __restrict__ leftbf,
    const unsigned short* __restrict__ T2,
    const float* __restrict__ bo, float* __restrict__ out) {
  const int ah = blockIdx.x;   // a-half (128 rows)
  const int b = blockIdx.y;
  const int t = threadIdx.x;
  const int w = t >> 6;
  const int l = t & 63;
  const int fl = l & 15;   // A row (f) / B col (a) / D col (a)
  const int lk = l >> 4;   // k-octet / D row-quad

  // B-operand fragments: left[a0 + m*16 + fl][lk*8 .. +7]
  bf16x8 lfrag[8];
#pragma unroll
  for (int m = 0; m < 8; ++m)
    lfrag[m] = *(const bf16x8*)(leftbf + (ah * 128 + m * 16 + fl) * C_N + lk * 8);

  // A-operand fragments: T[b][ft*16 + fl][lk*8 .. +7]
  bf16x8 tfrag[4];
#pragma unroll
  for (int q = 0; q < 4; ++q) {
    const int ft = w * 4 + q;
    tfrag[q] = *(const bf16x8*)(T2 + ((size_t)b * F_N + ft * 16 + fl) * C_N + lk * 8);
  }

  const size_t rowstride = (size_t)A_N * F_N;  // 65536
  const f32x4* bo4 = (const f32x4*)bo;
#pragma unroll
  for (int q = 0; q < 4; ++q) {
    const int ft = w * 4 + q;
    const f32x4 bv = bo4[ft * 4 + lk];
#pragma unroll
    for (int m = 0; m < 8; ++m) {
      f32x4 acc = bv;
      acc = __builtin_amdgcn_mfma_f32_16x16x32_bf16(tfrag[q], lfrag[m], acc, 0, 0, 0);
      const int a = ah * 128 + m * 16 + fl;
      *(f32x4*)(out + (size_t)a * rowstride + b * F_N + ft * 16 + lk * 4) = acc;
    }
  }
}

extern "C" void kernel_launch(void* const* d_in, const int* in_sizes, int n_in,
                              void* d_out, int out_size, void* d_ws, size_t ws_size,
                              hipStream_t stream) {
  const float* node_vec  = (const float*)d_in[0];
  const float* node_mask = (const float*)d_in[1];
  const float* ln_scale  = (const float*)d_in[2];
  const float* ln_bias   = (const float*)d_in[3];
  const float* Wl        = (const float*)d_in[4];
  const float* bl        = (const float*)d_in[5];
  const float* Wr        = (const float*)d_in[6];
  const float* br        = (const float*)d_in[7];
  const float* Wo        = (const float*)d_in[8];
  const float* bo        = (const float*)d_in[9];
  float* out = (float*)d_out;

  // ws: right f32 (32KB) | leftbf bf16 (16KB) | pad to 64KB | T2 bf16 [b][f][c] (4MB)
  float* right           = (float*)d_ws;
  unsigned short* leftbf = (unsigned short*)(right + A_N * C_N);
  unsigned short* T2     = (unsigned short*)((char*)d_ws + 65536);

  ln_proj_kernel<<<A_N, 256, 0, stream>>>(node_vec, node_mask, ln_scale, ln_bias,
                                          Wl, bl, Wr, br, leftbf, right);
  compT_kernel<<<dim3(64, 4), 256, 0, stream>>>(right, Wo, T2);
  out_mfma_kernel<<<dim3(2, A_N), 256, 0, stream>>>(leftbf, T2, bo, out);
}